// Round 1
// baseline (654.327 us; speedup 1.0000x reference)
//
#include <hip/hip_runtime.h>
#include <hip/hip_bf16.h>

#define BATCH 32
#define E 256
#define V 32000
#define NSTEP 128
#define M_TOTAL (BATCH * NSTEP)   // 4096

typedef __attribute__((ext_vector_type(4))) float f32x4;
typedef __attribute__((ext_vector_type(8))) short s16x8;

static __device__ __forceinline__ short f2bf(float v) {
    __hip_bfloat16 h = __float2bfloat16(v);
    return *reinterpret_cast<short*>(&h);
}

// ---------------------------------------------------------------------------
// Kernel 1: transpose + convert vocab_w (E x V, f32) -> wt (V x E, bf16)
// so MFMA B-fragments become 16B-contiguous loads.
// ---------------------------------------------------------------------------
__global__ __launch_bounds__(256) void transpose_w_kernel(const float* __restrict__ w,
                                                          short* __restrict__ wt) {
    __shared__ float tile[64][65];   // +1 pad: conflict-free transposed reads
    const int k0 = blockIdx.x * 64;  // 4 blocks over E=256
    const int n0 = blockIdx.y * 64;  // 500 blocks over V=32000
    const int c  = threadIdx.x & 63;
    const int r4 = threadIdx.x >> 6;

    #pragma unroll
    for (int r = r4; r < 64; r += 4)
        tile[r][c] = w[(size_t)(k0 + r) * V + n0 + c];
    __syncthreads();
    #pragma unroll
    for (int r = r4; r < 64; r += 4)
        wt[(size_t)(n0 + r) * E + k0 + c] = f2bf(tile[c][r]);
}

// ---------------------------------------------------------------------------
// Kernel 2: RNN trajectory. One block per batch element, fp32 throughout.
// z kept in LDS; emits stored as bf16 rows of zs (M_TOTAL x E).
// ---------------------------------------------------------------------------
__global__ __launch_bounds__(256) void traj_kernel(const float* __restrict__ latent,
                                                   const int* __restrict__ zi,
                                                   short* __restrict__ zsb) {
    __shared__ float z[E];
    __shared__ float red[8];
    const int b    = blockIdx.x;
    const int tid  = threadIdx.x;
    const int lane = tid & 63;
    const int wid  = tid >> 6;
    const float* tr = latent + (size_t)zi[b] * (E * E);

    z[tid] = tr[tid];               // z0 = trans[b, 0, :]
    __syncthreads();

    const float* col = tr + tid;    // column `tid` of trans (stride E)

    for (int t = 0; t < NSTEP; ++t) {
        // --- std(z, ddof=1): block reduce of sum and sumsq ---
        float v = z[tid];
        float s = v, s2 = v * v;
        #pragma unroll
        for (int m = 1; m < 64; m <<= 1) {
            s  += __shfl_xor(s, m);
            s2 += __shfl_xor(s2, m);
        }
        if (lane == 0) { red[wid] = s; red[wid + 4] = s2; }
        __syncthreads();
        float ts  = red[0] + red[1] + red[2] + red[3];
        float ts2 = red[4] + red[5] + red[6] + red[7];
        float mean = ts * (1.0f / 256.0f);
        float var  = (ts2 - 256.0f * mean * mean) * (1.0f / 255.0f);
        var = fmaxf(var, 0.0f);
        float scale = 0.113f / (1e-5f + sqrtf(var));

        // --- emit[f] = scale * sum_e z[e] * trans[e][f] (8-way ILP) ---
        float a0 = 0, a1 = 0, a2 = 0, a3 = 0, a4 = 0, a5 = 0, a6 = 0, a7 = 0;
        #pragma unroll
        for (int e = 0; e < E; e += 8) {
            a0 += z[e + 0] * col[(e + 0) << 8];
            a1 += z[e + 1] * col[(e + 1) << 8];
            a2 += z[e + 2] * col[(e + 2) << 8];
            a3 += z[e + 3] * col[(e + 3) << 8];
            a4 += z[e + 4] * col[(e + 4) << 8];
            a5 += z[e + 5] * col[(e + 5) << 8];
            a6 += z[e + 6] * col[(e + 6) << 8];
            a7 += z[e + 7] * col[(e + 7) << 8];
        }
        float emit = scale * (((a0 + a1) + (a2 + a3)) + ((a4 + a5) + (a6 + a7)));

        __syncthreads();            // all reads of z/red complete
        z[tid] = emit;
        zsb[((size_t)b * NSTEP + t) * E + tid] = f2bf(emit);
        __syncthreads();            // z ready for next step
    }
}

// ---------------------------------------------------------------------------
// Kernel 3: bf16 MFMA GEMM (4096 x 32000 x 256) with fused exp-rowsum and
// target-logit gather. 128x128 tile, 4 waves of 64x64, K looped 8 x 32.
// ---------------------------------------------------------------------------
__global__ __launch_bounds__(256) void gemm_lse_kernel(const short* __restrict__ zsb,
                                                       const short* __restrict__ wt,
                                                       const float* __restrict__ vb,
                                                       const int* __restrict__ y,
                                                       float* __restrict__ rowsum,
                                                       float* __restrict__ logit_y) {
    const int tid  = threadIdx.x;
    const int lane = tid & 63;
    const int w    = tid >> 6;
    const int m0 = blockIdx.x * 128 + (w >> 1) * 64;
    const int n0 = blockIdx.y * 128 + (w & 1) * 64;
    const int lm = lane & 15;        // M index (A) / N index (B)
    const int lk = lane >> 4;        // k-group

    f32x4 acc[4][4] = {};

    for (int k0 = 0; k0 < E; k0 += 32) {
        s16x8 af[4], bf[4];
        #pragma unroll
        for (int i = 0; i < 4; ++i)
            af[i] = *(const s16x8*)(zsb + (size_t)(m0 + i * 16 + lm) * E + k0 + lk * 8);
        #pragma unroll
        for (int j = 0; j < 4; ++j)
            bf[j] = *(const s16x8*)(wt + (size_t)(n0 + j * 16 + lm) * E + k0 + lk * 8);
        #pragma unroll
        for (int i = 0; i < 4; ++i)
            #pragma unroll
            for (int j = 0; j < 4; ++j)
                acc[i][j] = __builtin_amdgcn_mfma_f32_16x16x32_bf16(af[i], bf[j], acc[i][j], 0, 0, 0);
    }

    // Epilogue: C[m0+i*16+(lane>>4)*4+r][n0+j*16+(lane&15)] = acc[i][j][r]
    const int cr = lane >> 4;
    #pragma unroll
    for (int i = 0; i < 4; ++i) {
        const int rowbase = m0 + i * 16 + cr * 4;
        int yrow[4];
        #pragma unroll
        for (int r = 0; r < 4; ++r) yrow[r] = y[rowbase + r];

        float rs[4] = {0.f, 0.f, 0.f, 0.f};
        #pragma unroll
        for (int j = 0; j < 4; ++j) {
            const int n_g = n0 + j * 16 + lm;
            const float bias = vb[n_g];
            #pragma unroll
            for (int r = 0; r < 4; ++r) {
                float logit = acc[i][j][r] + bias;
                if (n_g == yrow[r]) logit_y[rowbase + r] = logit;
                rs[r] += __expf(logit);
            }
        }
        // reduce over the 16 columns held by lanes sharing (lane>>4)
        #pragma unroll
        for (int m = 1; m < 16; m <<= 1)
            #pragma unroll
            for (int r = 0; r < 4; ++r) rs[r] += __shfl_xor(rs[r], m);
        if (lm == 0) {
            #pragma unroll
            for (int r = 0; r < 4; ++r) atomicAdd(&rowsum[rowbase + r], rs[r]);
        }
    }
}

// ---------------------------------------------------------------------------
// Kernel 4: yp[row] = logit_y[row] - log(sum_exp[row])
// ---------------------------------------------------------------------------
__global__ __launch_bounds__(256) void finalize_kernel(const float* __restrict__ rowsum,
                                                       const float* __restrict__ logit_y,
                                                       float* __restrict__ out) {
    int i = blockIdx.x * 256 + threadIdx.x;
    if (i < M_TOTAL) out[i] = logit_y[i] - logf(rowsum[i]);
}

// ---------------------------------------------------------------------------
extern "C" void kernel_launch(void* const* d_in, const int* in_sizes, int n_in,
                              void* d_out, int out_size, void* d_ws, size_t ws_size,
                              hipStream_t stream) {
    const float* latent  = (const float*)d_in[0];
    const float* vocab_w = (const float*)d_in[1];
    const float* vocab_b = (const float*)d_in[2];
    const int*   zi      = (const int*)d_in[3];
    const int*   y       = (const int*)d_in[4];
    float* out = (float*)d_out;

    char* ws = (char*)d_ws;
    float* rowsum  = (float*)(ws);                       // 4096 f32
    float* logit_y = (float*)(ws + 16384);               // 4096 f32
    short* zsb     = (short*)(ws + 32768);               // 4096*256 bf16 = 2 MB
    short* wt      = (short*)(ws + 32768 + 2097152);     // 32000*256 bf16 = 16 MB

    hipMemsetAsync(rowsum, 0, M_TOTAL * sizeof(float), stream);

    hipLaunchKernelGGL(transpose_w_kernel, dim3(4, 500), dim3(256), 0, stream, vocab_w, wt);
    hipLaunchKernelGGL(traj_kernel, dim3(BATCH), dim3(256), 0, stream, latent, zi, zsb);
    hipLaunchKernelGGL(gemm_lse_kernel, dim3(M_TOTAL / 128, V / 128), dim3(256), 0, stream,
                       zsb, wt, vocab_b, y, rowsum, logit_y);
    hipLaunchKernelGGL(finalize_kernel, dim3((M_TOTAL + 255) / 256), dim3(256), 0, stream,
                       rowsum, logit_y, out);
}

// Round 2
// 390.944 us; speedup vs baseline: 1.6737x; 1.6737x over previous
//
#include <hip/hip_runtime.h>
#include <hip/hip_bf16.h>

#define BATCH 32
#define E 256
#define V 32000
#define NSTEP 128
#define M_TOTAL (BATCH * NSTEP)   // 4096

typedef __attribute__((ext_vector_type(4))) float f32x4;
typedef __attribute__((ext_vector_type(8))) short s16x8;

static __device__ __forceinline__ short f2bf(float v) {
    __hip_bfloat16 h = __float2bfloat16(v);
    return *reinterpret_cast<short*>(&h);
}

// ---------------------------------------------------------------------------
// Kernel 1: transpose + convert vocab_w (E x V, f32) -> wt (V x E, bf16)
// ---------------------------------------------------------------------------
__global__ __launch_bounds__(256) void transpose_w_kernel(const float* __restrict__ w,
                                                          short* __restrict__ wt) {
    __shared__ float tile[64][65];
    const int k0 = blockIdx.x * 64;
    const int n0 = blockIdx.y * 64;
    const int c  = threadIdx.x & 63;
    const int r4 = threadIdx.x >> 6;

    #pragma unroll
    for (int r = r4; r < 64; r += 4)
        tile[r][c] = w[(size_t)(k0 + r) * V + n0 + c];
    __syncthreads();
    #pragma unroll
    for (int r = r4; r < 64; r += 4)
        wt[(size_t)(n0 + r) * E + k0 + c] = f2bf(tile[c][r]);
}

// ---------------------------------------------------------------------------
// Kernel 2: RNN trajectory, weights-in-registers version.
// 1024 threads/block, 1 block/batch. Thread (r=tid>>8, f=tid&255) owns
// trans[r*64 .. r*64+63][f] in 64 VGPRs. Per step: 64 reg-FMAs against
// broadcast LDS z, 4-way partial reduce, fused std reduce on waves 0-3.
// ---------------------------------------------------------------------------
__global__ __launch_bounds__(1024) void traj_kernel(const float* __restrict__ latent,
                                                    const int* __restrict__ zi,
                                                    short* __restrict__ zsb) {
    __shared__ float z[E];
    __shared__ float part[4][E];
    __shared__ float red[8];

    const int b    = blockIdx.x;
    const int tid  = threadIdx.x;
    const int f    = tid & 255;
    const int r    = tid >> 8;        // 0..3
    const int lane = tid & 63;
    const int wid  = tid >> 6;        // 0..15
    const float* tr = latent + (size_t)zi[b] * (E * E);

    // Load this thread's weight column chunk: w[k] = trans[r*64+k][f]
    float wreg[64];
    #pragma unroll
    for (int k = 0; k < 64; ++k)
        wreg[k] = tr[(size_t)((r * 64 + k) << 8) + f];

    // z0 = trans[b, 0, :]
    if (r == 0) z[f] = tr[f];
    __syncthreads();

    const float* zp = z + r * 64;

    for (int t = 0; t < NSTEP; ++t) {
        // --- partial dot over this thread's e-chunk (reg weights, LDS z) ---
        float a0 = 0.f, a1 = 0.f, a2 = 0.f, a3 = 0.f;
        #pragma unroll
        for (int k = 0; k < 64; k += 4) {
            a0 += zp[k + 0] * wreg[k + 0];
            a1 += zp[k + 1] * wreg[k + 1];
            a2 += zp[k + 2] * wreg[k + 2];
            a3 += zp[k + 3] * wreg[k + 3];
        }
        part[r][f] = (a0 + a1) + (a2 + a3);

        // --- waves 0-3 concurrently reduce sum/sumsq of z for std ---
        if (r == 0) {
            float v = z[f];
            float s = v, s2 = v * v;
            #pragma unroll
            for (int m = 1; m < 64; m <<= 1) {
                s  += __shfl_xor(s, m);
                s2 += __shfl_xor(s2, m);
            }
            if (lane == 0) { red[wid] = s; red[wid + 4] = s2; }
        }
        __syncthreads();   // part + red visible; all z reads done

        float ts   = red[0] + red[1] + red[2] + red[3];
        float ts2  = red[4] + red[5] + red[6] + red[7];
        float mean = ts * (1.0f / 256.0f);
        float var  = fmaxf((ts2 - 256.0f * mean * mean) * (1.0f / 255.0f), 0.0f);
        float scale = 0.113f / (1e-5f + sqrtf(var));

        if (r == 0) {
            float tot  = part[0][f] + part[1][f] + part[2][f] + part[3][f];
            float emit = scale * tot;
            z[f] = emit;
            zsb[((size_t)b * NSTEP + t) * E + f] = f2bf(emit);
        }
        __syncthreads();   // z updated for next step
    }
}

// ---------------------------------------------------------------------------
// Kernel 3: bf16 MFMA GEMM (4096 x 32000 x 256) with fused exp-rowsum and
// target-logit gather. 128x128 tile, 4 waves of 64x64, K looped 8 x 32.
// ---------------------------------------------------------------------------
__global__ __launch_bounds__(256) void gemm_lse_kernel(const short* __restrict__ zsb,
                                                       const short* __restrict__ wt,
                                                       const float* __restrict__ vb,
                                                       const int* __restrict__ y,
                                                       float* __restrict__ rowsum,
                                                       float* __restrict__ logit_y) {
    const int tid  = threadIdx.x;
    const int lane = tid & 63;
    const int w    = tid >> 6;
    const int m0 = blockIdx.x * 128 + (w >> 1) * 64;
    const int n0 = blockIdx.y * 128 + (w & 1) * 64;
    const int lm = lane & 15;
    const int lk = lane >> 4;

    f32x4 acc[4][4] = {};

    for (int k0 = 0; k0 < E; k0 += 32) {
        s16x8 af[4], bf[4];
        #pragma unroll
        for (int i = 0; i < 4; ++i)
            af[i] = *(const s16x8*)(zsb + (size_t)(m0 + i * 16 + lm) * E + k0 + lk * 8);
        #pragma unroll
        for (int j = 0; j < 4; ++j)
            bf[j] = *(const s16x8*)(wt + (size_t)(n0 + j * 16 + lm) * E + k0 + lk * 8);
        #pragma unroll
        for (int i = 0; i < 4; ++i)
            #pragma unroll
            for (int j = 0; j < 4; ++j)
                acc[i][j] = __builtin_amdgcn_mfma_f32_16x16x32_bf16(af[i], bf[j], acc[i][j], 0, 0, 0);
    }

    const int cr = lane >> 4;
    #pragma unroll
    for (int i = 0; i < 4; ++i) {
        const int rowbase = m0 + i * 16 + cr * 4;
        int yrow[4];
        #pragma unroll
        for (int r = 0; r < 4; ++r) yrow[r] = y[rowbase + r];

        float rs[4] = {0.f, 0.f, 0.f, 0.f};
        #pragma unroll
        for (int j = 0; j < 4; ++j) {
            const int n_g = n0 + j * 16 + lm;
            const float bias = vb[n_g];
            #pragma unroll
            for (int r = 0; r < 4; ++r) {
                float logit = acc[i][j][r] + bias;
                if (n_g == yrow[r]) logit_y[rowbase + r] = logit;
                rs[r] += __expf(logit);
            }
        }
        #pragma unroll
        for (int m = 1; m < 16; m <<= 1)
            #pragma unroll
            for (int r = 0; r < 4; ++r) rs[r] += __shfl_xor(rs[r], m);
        if (lm == 0) {
            #pragma unroll
            for (int r = 0; r < 4; ++r) atomicAdd(&rowsum[rowbase + r], rs[r]);
        }
    }
}

// ---------------------------------------------------------------------------
// Kernel 4: yp[row] = logit_y[row] - log(sum_exp[row])
// ---------------------------------------------------------------------------
__global__ __launch_bounds__(256) void finalize_kernel(const float* __restrict__ rowsum,
                                                       const float* __restrict__ logit_y,
                                                       float* __restrict__ out) {
    int i = blockIdx.x * 256 + threadIdx.x;
    if (i < M_TOTAL) out[i] = logit_y[i] - logf(rowsum[i]);
}

// ---------------------------------------------------------------------------
extern "C" void kernel_launch(void* const* d_in, const int* in_sizes, int n_in,
                              void* d_out, int out_size, void* d_ws, size_t ws_size,
                              hipStream_t stream) {
    const float* latent  = (const float*)d_in[0];
    const float* vocab_w = (const float*)d_in[1];
    const float* vocab_b = (const float*)d_in[2];
    const int*   zi      = (const int*)d_in[3];
    const int*   y       = (const int*)d_in[4];
    float* out = (float*)d_out;

    char* ws = (char*)d_ws;
    float* rowsum  = (float*)(ws);                       // 4096 f32
    float* logit_y = (float*)(ws + 16384);               // 4096 f32
    short* zsb     = (short*)(ws + 32768);               // 2 MB
    short* wt      = (short*)(ws + 32768 + 2097152);     // 16 MB

    hipMemsetAsync(rowsum, 0, M_TOTAL * sizeof(float), stream);

    hipLaunchKernelGGL(transpose_w_kernel, dim3(4, 500), dim3(256), 0, stream, vocab_w, wt);
    hipLaunchKernelGGL(traj_kernel, dim3(BATCH), dim3(1024), 0, stream, latent, zi, zsb);
    hipLaunchKernelGGL(gemm_lse_kernel, dim3(M_TOTAL / 128, V / 128), dim3(256), 0, stream,
                       zsb, wt, vocab_b, y, rowsum, logit_y);
    hipLaunchKernelGGL(finalize_kernel, dim3((M_TOTAL + 255) / 256), dim3(256), 0, stream,
                       rowsum, logit_y, out);
}

// Round 3
// 377.615 us; speedup vs baseline: 1.7328x; 1.0353x over previous
//
#include <hip/hip_runtime.h>
#include <hip/hip_bf16.h>

#define BATCH 32
#define E 256
#define V 32000
#define NSTEP 128
#define M_TOTAL (BATCH * NSTEP)   // 4096
#define BM 128
#define BN 128
#define NBN (V / BN)              // 250

typedef __attribute__((ext_vector_type(4))) float f32x4;
typedef __attribute__((ext_vector_type(8))) short s16x8;

static __device__ __forceinline__ short f2bf(float v) {
    __hip_bfloat16 h = __float2bfloat16(v);
    return *reinterpret_cast<short*>(&h);
}

static __device__ __forceinline__ void gload_lds16(const void* g, void* l) {
    __builtin_amdgcn_global_load_lds((const __attribute__((address_space(1))) void*)g,
                                     (__attribute__((address_space(3))) void*)l,
                                     16, 0, 0);
}

// ---------------------------------------------------------------------------
// Kernel 1: transpose + convert vocab_w (E x V, f32) -> wt (V x E, bf16)
// ---------------------------------------------------------------------------
__global__ __launch_bounds__(256) void transpose_w_kernel(const float* __restrict__ w,
                                                          short* __restrict__ wt) {
    __shared__ float tile[64][65];
    const int k0 = blockIdx.x * 64;
    const int n0 = blockIdx.y * 64;
    const int c  = threadIdx.x & 63;
    const int r4 = threadIdx.x >> 6;

    #pragma unroll
    for (int r = r4; r < 64; r += 4)
        tile[r][c] = w[(size_t)(k0 + r) * V + n0 + c];
    __syncthreads();
    #pragma unroll
    for (int r = r4; r < 64; r += 4)
        wt[(size_t)(n0 + r) * E + k0 + c] = f2bf(tile[c][r]);
}

// ---------------------------------------------------------------------------
// Kernel 2: RNN trajectory, weights-in-registers; z read via ds_read_b128.
// ---------------------------------------------------------------------------
__global__ __launch_bounds__(1024) void traj_kernel(const float* __restrict__ latent,
                                                    const int* __restrict__ zi,
                                                    short* __restrict__ zsb) {
    __shared__ __align__(16) float z[E];
    __shared__ float part[4][E];
    __shared__ float red[8];

    const int b    = blockIdx.x;
    const int tid  = threadIdx.x;
    const int f    = tid & 255;
    const int r    = tid >> 8;        // 0..3
    const int lane = tid & 63;
    const int wid  = tid >> 6;        // 0..15
    const float* tr = latent + (size_t)zi[b] * (E * E);

    float wreg[64];
    #pragma unroll
    for (int k = 0; k < 64; ++k)
        wreg[k] = tr[(size_t)((r * 64 + k) << 8) + f];

    if (r == 0) z[f] = tr[f];
    __syncthreads();

    const float* zp = z + r * 64;

    for (int t = 0; t < NSTEP; ++t) {
        float a0 = 0.f, a1 = 0.f, a2 = 0.f, a3 = 0.f;
        #pragma unroll
        for (int k = 0; k < 64; k += 4) {
            f32x4 zv = *(const f32x4*)(zp + k);
            a0 += zv[0] * wreg[k + 0];
            a1 += zv[1] * wreg[k + 1];
            a2 += zv[2] * wreg[k + 2];
            a3 += zv[3] * wreg[k + 3];
        }
        part[r][f] = (a0 + a1) + (a2 + a3);

        if (r == 0) {
            float v = z[f];
            float s = v, s2 = v * v;
            #pragma unroll
            for (int m = 1; m < 64; m <<= 1) {
                s  += __shfl_xor(s, m);
                s2 += __shfl_xor(s2, m);
            }
            if (lane == 0) { red[wid] = s; red[wid + 4] = s2; }
        }
        __syncthreads();

        float ts   = red[0] + red[1] + red[2] + red[3];
        float ts2  = red[4] + red[5] + red[6] + red[7];
        float mean = ts * (1.0f / 256.0f);
        float var  = fmaxf((ts2 - 256.0f * mean * mean) * (1.0f / 255.0f), 0.0f);
        float scale = 0.113f / (1e-5f + sqrtf(var));

        if (r == 0) {
            float tot  = part[0][f] + part[1][f] + part[2][f] + part[3][f];
            float emit = scale * tot;
            z[f] = emit;
            zsb[((size_t)b * NSTEP + t) * E + f] = f2bf(emit);
        }
        __syncthreads();
    }
}

// ---------------------------------------------------------------------------
// Kernel 3: panel-resident GEMM + fused LSE partials.
// B panel [128][256] bf16 staged once in LDS (XOR-swizzled, gload_lds 16B);
// A (64 rows x 256) per wave in registers; 128 MFMA/wave, one barrier total.
// ---------------------------------------------------------------------------
__global__ __launch_bounds__(256, 2) void gemm_lse_kernel(const short* __restrict__ zsb,
                                                          const short* __restrict__ wt,
                                                          const float* __restrict__ vb,
                                                          const int* __restrict__ y,
                                                          float* __restrict__ partial,
                                                          float* __restrict__ logit_y) {
    __shared__ short bpan[BN * E];    // 64 KB

    const int tid  = threadIdx.x;
    const int lane = tid & 63;
    const int w    = tid >> 6;

    // XCD-aware remap: each XCD gets a contiguous stripe ordered bm-fast,
    // so the 32 m-blocks sharing a B panel run back-to-back on one XCD.
    const int bid = blockIdx.x;               // 0..7999, 8000 % 8 == 0
    const int g   = (bid & 7) * (M_TOTAL / BM * NBN / 8) + (bid >> 3);
    const int bn  = g >> 5;                   // 0..249
    const int bm  = g & 31;                   // 0..31
    const int n0  = bn * BN;
    const int m0  = bm * BM;

    // ---- stage B panel: linear LDS dest, inverse-swizzled global source ----
    #pragma unroll
    for (int i = 0; i < 16; ++i) {
        const int c   = i * 4 + w;                 // 1 KB chunk id, wave-uniform
        const int p   = c * 1024 + lane * 16;      // this lane's LDS byte
        const int row = p >> 9;                    // local n row (512 B/row)
        const int bl  = (p & 511) ^ ((row & 7) << 4);
        gload_lds16((const char*)wt + (size_t)(n0 + row) * (E * 2) + bl,
                    (char*)bpan + c * 1024);
    }

    // ---- A panel into registers: 64 rows x 256 k per wave ----
    const int wr = w >> 1, wc = w & 1;
    const int lm = lane & 15, lk = lane >> 4;
    const int mw = m0 + wr * 64;

    s16x8 a[4][8];
    #pragma unroll
    for (int rt = 0; rt < 4; ++rt)
        #pragma unroll
        for (int kk = 0; kk < 8; ++kk)
            a[rt][kk] = *(const s16x8*)(zsb + (size_t)(mw + rt * 16 + lm) * E + kk * 32 + lk * 8);

    __syncthreads();   // drains vmcnt: B in LDS, A in regs

    // ---- MFMA: 32 swizzled ds_read_b128 + 128 MFMA per wave ----
    f32x4 acc[4][4] = {};   // [rt][nt]
    #pragma unroll
    for (int nt = 0; nt < 4; ++nt) {
        const int n_loc = wc * 64 + nt * 16 + lm;
        const int sw    = (n_loc & 7) << 4;
        #pragma unroll
        for (int kk = 0; kk < 8; ++kk) {
            const int lin = n_loc * 512 + kk * 64 + lk * 16;
            s16x8 bf = *(const s16x8*)((const char*)bpan + (lin ^ sw));
            #pragma unroll
            for (int rt = 0; rt < 4; ++rt)
                acc[rt][nt] = __builtin_amdgcn_mfma_f32_16x16x32_bf16(a[rt][kk], bf, acc[rt][nt], 0, 0, 0);
        }
    }

    // ---- epilogue: bias, exp-rowsum over this wave's 64 cols, target gather ----
    const int cr = lane >> 4;
    #pragma unroll
    for (int rt = 0; rt < 4; ++rt) {
        const int rowbase = mw + rt * 16 + cr * 4;
        int yr[4];
        #pragma unroll
        for (int r = 0; r < 4; ++r) yr[r] = y[rowbase + r];

        float rs[4] = {0.f, 0.f, 0.f, 0.f};
        #pragma unroll
        for (int nt = 0; nt < 4; ++nt) {
            const int n_g  = n0 + wc * 64 + nt * 16 + lm;
            const float bias = vb[n_g];
            #pragma unroll
            for (int r = 0; r < 4; ++r) {
                float logit = acc[rt][nt][r] + bias;
                if (n_g == yr[r]) logit_y[rowbase + r] = logit;
                rs[r] += __expf(logit);
            }
        }
        #pragma unroll
        for (int m = 1; m < 16; m <<= 1)
            #pragma unroll
            for (int r = 0; r < 4; ++r) rs[r] += __shfl_xor(rs[r], m);
        if (lm == 0) {
            #pragma unroll
            for (int r = 0; r < 4; ++r)
                partial[(size_t)(bn * 2 + wc) * M_TOTAL + rowbase + r] = rs[r];
        }
    }
}

// ---------------------------------------------------------------------------
// Kernel 4: yp[row] = logit_y[row] - log(sum over 500 partials)
// ---------------------------------------------------------------------------
__global__ __launch_bounds__(256) void finalize_kernel(const float* __restrict__ partial,
                                                       const float* __restrict__ logit_y,
                                                       float* __restrict__ out) {
    const int row = blockIdx.x * 256 + threadIdx.x;
    float s0 = 0.f, s1 = 0.f, s2 = 0.f, s3 = 0.f;
    for (int j = 0; j < 2 * NBN; j += 4) {
        s0 += partial[(size_t)(j + 0) * M_TOTAL + row];
        s1 += partial[(size_t)(j + 1) * M_TOTAL + row];
        s2 += partial[(size_t)(j + 2) * M_TOTAL + row];
        s3 += partial[(size_t)(j + 3) * M_TOTAL + row];
    }
    out[row] = logit_y[row] - logf((s0 + s1) + (s2 + s3));
}

// ---------------------------------------------------------------------------
extern "C" void kernel_launch(void* const* d_in, const int* in_sizes, int n_in,
                              void* d_out, int out_size, void* d_ws, size_t ws_size,
                              hipStream_t stream) {
    const float* latent  = (const float*)d_in[0];
    const float* vocab_w = (const float*)d_in[1];
    const float* vocab_b = (const float*)d_in[2];
    const int*   zi      = (const int*)d_in[3];
    const int*   y       = (const int*)d_in[4];
    float* out = (float*)d_out;

    char* ws = (char*)d_ws;
    float* logit_y = (float*)(ws);                                  // 16 KB
    float* partial = (float*)(ws + 16384);                          // 500*4096*4 = 8 MB
    short* zsb     = (short*)(ws + 16384 + 8192000);                // 2 MB
    short* wt      = (short*)(ws + 16384 + 8192000 + 2097152);      // 16 MB

    hipLaunchKernelGGL(transpose_w_kernel, dim3(4, 500), dim3(256), 0, stream, vocab_w, wt);
    hipLaunchKernelGGL(traj_kernel, dim3(BATCH), dim3(1024), 0, stream, latent, zi, zsb);
    hipLaunchKernelGGL(gemm_lse_kernel, dim3(32 * NBN), dim3(256), 0, stream,
                       zsb, wt, vocab_b, y, partial, logit_y);
    hipLaunchKernelGGL(finalize_kernel, dim3(M_TOTAL / 256), dim3(256), 0, stream,
                       partial, logit_y, out);
}

// Round 4
// 330.731 us; speedup vs baseline: 1.9784x; 1.1418x over previous
//
#include <hip/hip_runtime.h>
#include <hip/hip_bf16.h>

#define BATCH 32
#define E 256
#define V 32000
#define NSTEP 128
#define M_TOTAL (BATCH * NSTEP)   // 4096
#define BM 256
#define BN 128
#define NBN (V / BN)              // 250

typedef __attribute__((ext_vector_type(4))) float f32x4;
typedef __attribute__((ext_vector_type(8))) short s16x8;

static __device__ __forceinline__ short f2bf(float v) {
    __hip_bfloat16 h = __float2bfloat16(v);
    return *reinterpret_cast<short*>(&h);
}

static __device__ __forceinline__ void gload_lds16(const void* g, void* l) {
    __builtin_amdgcn_global_load_lds((const __attribute__((address_space(1))) void*)g,
                                     (__attribute__((address_space(3))) void*)l,
                                     16, 0, 0);
}

// ---------------------------------------------------------------------------
// Kernel 1: transpose + convert vocab_w (E x V, f32) -> wt (V x E, bf16)
// ---------------------------------------------------------------------------
__global__ __launch_bounds__(256) void transpose_w_kernel(const float* __restrict__ w,
                                                          short* __restrict__ wt) {
    __shared__ float tile[64][65];
    const int k0 = blockIdx.x * 64;
    const int n0 = blockIdx.y * 64;
    const int c  = threadIdx.x & 63;
    const int r4 = threadIdx.x >> 6;

    #pragma unroll
    for (int r = r4; r < 64; r += 4)
        tile[r][c] = w[(size_t)(k0 + r) * V + n0 + c];
    __syncthreads();
    #pragma unroll
    for (int r = r4; r < 64; r += 4)
        wt[(size_t)(n0 + r) * E + k0 + c] = f2bf(tile[c][r]);
}

// ---------------------------------------------------------------------------
// Kernel 2: RNN trajectory, weights-in-registers (unchanged this round).
// ---------------------------------------------------------------------------
__global__ __launch_bounds__(1024) void traj_kernel(const float* __restrict__ latent,
                                                    const int* __restrict__ zi,
                                                    short* __restrict__ zsb) {
    __shared__ __align__(16) float z[E];
    __shared__ float part[4][E];
    __shared__ float red[8];

    const int b    = blockIdx.x;
    const int tid  = threadIdx.x;
    const int f    = tid & 255;
    const int r    = tid >> 8;        // 0..3
    const int lane = tid & 63;
    const int wid  = tid >> 6;        // 0..15
    const float* tr = latent + (size_t)zi[b] * (E * E);

    float wreg[64];
    #pragma unroll
    for (int k = 0; k < 64; ++k)
        wreg[k] = tr[(size_t)((r * 64 + k) << 8) + f];

    if (r == 0) z[f] = tr[f];
    __syncthreads();

    const float* zp = z + r * 64;

    for (int t = 0; t < NSTEP; ++t) {
        float a0 = 0.f, a1 = 0.f, a2 = 0.f, a3 = 0.f;
        #pragma unroll
        for (int k = 0; k < 64; k += 4) {
            f32x4 zv = *(const f32x4*)(zp + k);
            a0 += zv[0] * wreg[k + 0];
            a1 += zv[1] * wreg[k + 1];
            a2 += zv[2] * wreg[k + 2];
            a3 += zv[3] * wreg[k + 3];
        }
        part[r][f] = (a0 + a1) + (a2 + a3);

        if (r == 0) {
            float v = z[f];
            float s = v, s2 = v * v;
            #pragma unroll
            for (int m = 1; m < 64; m <<= 1) {
                s  += __shfl_xor(s, m);
                s2 += __shfl_xor(s2, m);
            }
            if (lane == 0) { red[wid] = s; red[wid + 4] = s2; }
        }
        __syncthreads();

        float ts   = red[0] + red[1] + red[2] + red[3];
        float ts2  = red[4] + red[5] + red[6] + red[7];
        float mean = ts * (1.0f / 256.0f);
        float var  = fmaxf((ts2 - 256.0f * mean * mean) * (1.0f / 255.0f), 0.0f);
        float scale = 0.113f / (1e-5f + sqrtf(var));

        if (r == 0) {
            float tot  = part[0][f] + part[1][f] + part[2][f] + part[3][f];
            float emit = scale * tot;
            z[f] = emit;
            zsb[((size_t)b * NSTEP + t) * E + f] = f2bf(emit);
        }
        __syncthreads();
    }
}

// ---------------------------------------------------------------------------
// Kernel 3: 256x128-tile GEMM + fused LSE partials.
// B panel [128][256] bf16 in LDS (swizzled gload_lds, 64 KB -> 2 blocks/CU);
// 512 threads = 8 waves (4 row x 2 col), each wave 64x64 output (acc = 64
// VGPR). A streamed from L2 as per-kk fragments (compiler-pipelined, 4
// waves/SIMD TLP). One barrier total.
// ---------------------------------------------------------------------------
__global__ __launch_bounds__(512, 4) void gemm_lse_kernel(const short* __restrict__ zsb,
                                                          const short* __restrict__ wt,
                                                          const float* __restrict__ vb,
                                                          const int* __restrict__ y,
                                                          float* __restrict__ partial,
                                                          float* __restrict__ logit_y) {
    __shared__ short bpan[BN * E];    // 64 KB

    const int tid  = threadIdx.x;
    const int lane = tid & 63;
    const int w    = tid >> 6;        // 0..7

    // Bijective XCD remap, bm-fast within each XCD stripe (4000 = 8 * 500).
    const int bid = blockIdx.x;
    const int g   = (bid & 7) * 500 + (bid >> 3);
    const int bn  = g >> 4;                   // 0..249
    const int bm  = g & 15;                   // 0..15
    const int n0  = bn * BN;
    const int m0  = bm * BM;

    // ---- stage B panel: linear LDS dest, inverse-swizzled global source ----
    #pragma unroll
    for (int i = 0; i < 8; ++i) {
        const int c   = i * 8 + w;                 // 1 KB chunk id, wave-uniform
        const int p   = c * 1024 + lane * 16;
        const int row = p >> 9;                    // local n row (512 B/row)
        const int bl  = (p & 511) ^ ((row & 7) << 4);
        gload_lds16((const char*)wt + (size_t)(n0 + row) * (E * 2) + bl,
                    (char*)bpan + c * 1024);
    }

    const int wr = w >> 1, wc = w & 1;
    const int lm = lane & 15, lk = lane >> 4;
    const int mw = m0 + wr * 64;

    __syncthreads();   // drains vmcnt: B panel resident

    // ---- K loop: per kk, 4 A-frags (global) + 4 B-frags (LDS) -> 16 MFMA ----
    f32x4 acc[4][4] = {};   // [rt][nt]
    #pragma unroll
    for (int kk = 0; kk < 8; ++kk) {
        s16x8 a[4], bfr[4];
        #pragma unroll
        for (int rt = 0; rt < 4; ++rt)
            a[rt] = *(const s16x8*)(zsb + (size_t)(mw + rt * 16 + lm) * E + kk * 32 + lk * 8);
        #pragma unroll
        for (int nt = 0; nt < 4; ++nt) {
            const int n_loc = wc * 64 + nt * 16 + lm;
            const int lin   = n_loc * 512 + kk * 64 + lk * 16;
            bfr[nt] = *(const s16x8*)((const char*)bpan + (lin ^ ((n_loc & 7) << 4)));
        }
        #pragma unroll
        for (int rt = 0; rt < 4; ++rt)
            #pragma unroll
            for (int nt = 0; nt < 4; ++nt)
                acc[rt][nt] = __builtin_amdgcn_mfma_f32_16x16x32_bf16(a[rt], bfr[nt], acc[rt][nt], 0, 0, 0);
    }

    // ---- epilogue: bias, exp-rowsum over this wave's 64 cols, target gather ----
    const int cr = lane >> 4;
    #pragma unroll
    for (int rt = 0; rt < 4; ++rt) {
        const int rowbase = mw + rt * 16 + cr * 4;
        int yr[4];
        #pragma unroll
        for (int r = 0; r < 4; ++r) yr[r] = y[rowbase + r];

        float rs[4] = {0.f, 0.f, 0.f, 0.f};
        #pragma unroll
        for (int nt = 0; nt < 4; ++nt) {
            const int n_g  = n0 + wc * 64 + nt * 16 + lm;
            const float bias = vb[n_g];
            #pragma unroll
            for (int r = 0; r < 4; ++r) {
                float logit = acc[rt][nt][r] + bias;
                if (n_g == yr[r]) logit_y[rowbase + r] = logit;
                rs[r] += __expf(logit);
            }
        }
        #pragma unroll
        for (int m = 1; m < 16; m <<= 1)
            #pragma unroll
            for (int r = 0; r < 4; ++r) rs[r] += __shfl_xor(rs[r], m);
        if (lm == 0) {
            #pragma unroll
            for (int r = 0; r < 4; ++r)
                partial[(size_t)(bn * 2 + wc) * M_TOTAL + rowbase + r] = rs[r];
        }
    }
}

// ---------------------------------------------------------------------------
// Kernel 4: yp[row] = logit_y[row] - log(sum over 500 partials)
// ---------------------------------------------------------------------------
__global__ __launch_bounds__(256) void finalize_kernel(const float* __restrict__ partial,
                                                       const float* __restrict__ logit_y,
                                                       float* __restrict__ out) {
    const int row = blockIdx.x * 256 + threadIdx.x;
    float s0 = 0.f, s1 = 0.f, s2 = 0.f, s3 = 0.f;
    for (int j = 0; j < 2 * NBN; j += 4) {
        s0 += partial[(size_t)(j + 0) * M_TOTAL + row];
        s1 += partial[(size_t)(j + 1) * M_TOTAL + row];
        s2 += partial[(size_t)(j + 2) * M_TOTAL + row];
        s3 += partial[(size_t)(j + 3) * M_TOTAL + row];
    }
    out[row] = logit_y[row] - logf((s0 + s1) + (s2 + s3));
}

// ---------------------------------------------------------------------------
extern "C" void kernel_launch(void* const* d_in, const int* in_sizes, int n_in,
                              void* d_out, int out_size, void* d_ws, size_t ws_size,
                              hipStream_t stream) {
    const float* latent  = (const float*)d_in[0];
    const float* vocab_w = (const float*)d_in[1];
    const float* vocab_b = (const float*)d_in[2];
    const int*   zi      = (const int*)d_in[3];
    const int*   y       = (const int*)d_in[4];
    float* out = (float*)d_out;

    char* ws = (char*)d_ws;
    float* logit_y = (float*)(ws);                                  // 16 KB
    float* partial = (float*)(ws + 16384);                          // 500*4096*4 = 8 MB
    short* zsb     = (short*)(ws + 16384 + 8192000);                // 2 MB
    short* wt      = (short*)(ws + 16384 + 8192000 + 2097152);      // 16 MB

    hipLaunchKernelGGL(transpose_w_kernel, dim3(4, 500), dim3(256), 0, stream, vocab_w, wt);
    hipLaunchKernelGGL(traj_kernel, dim3(BATCH), dim3(1024), 0, stream, latent, zi, zsb);
    hipLaunchKernelGGL(gemm_lse_kernel, dim3(16 * NBN), dim3(512), 0, stream,
                       zsb, wt, vocab_b, y, partial, logit_y);
    hipLaunchKernelGGL(finalize_kernel, dim3(M_TOTAL / 256), dim3(256), 0, stream,
                       partial, logit_y, out);
}

// Round 5
// 247.828 us; speedup vs baseline: 2.6402x; 1.3345x over previous
//
#include <hip/hip_runtime.h>
#include <hip/hip_bf16.h>

#define BATCH 32
#define E 256
#define V 32000
#define NSTEP 128
#define M_TOTAL (BATCH * NSTEP)   // 4096
#define BM 256
#define BN 128
#define NBN (V / BN)              // 250

typedef __attribute__((ext_vector_type(4))) float f32x4;
typedef __attribute__((ext_vector_type(8))) short s16x8;

static __device__ __forceinline__ short f2bf(float v) {
    __hip_bfloat16 h = __float2bfloat16(v);
    return *reinterpret_cast<short*>(&h);
}

static __device__ __forceinline__ void gload_lds16(const void* g, void* l) {
    __builtin_amdgcn_global_load_lds((const __attribute__((address_space(1))) void*)g,
                                     (__attribute__((address_space(3))) void*)l,
                                     16, 0, 0);
}

// DPP row_ror reduction within each 16-lane row (VALU pipe, no LDS traffic).
template<int CTRL>
static __device__ __forceinline__ float dpp_add(float v) {
    int i = __builtin_amdgcn_update_dpp(0, __builtin_bit_cast(int, v), CTRL, 0xF, 0xF, false);
    return v + __builtin_bit_cast(float, i);
}
static __device__ __forceinline__ float row16_sum(float v) {
    v = dpp_add<0x121>(v);   // row_ror:1
    v = dpp_add<0x122>(v);   // row_ror:2
    v = dpp_add<0x124>(v);   // row_ror:4
    v = dpp_add<0x128>(v);   // row_ror:8
    return v;
}

// ---------------------------------------------------------------------------
// Kernel 1 (merged): blocks 0..31 = RNN trajectory (MFMA, trans-in-regs);
// blocks 32.. = vocab_w transpose (fills the other 224 CUs concurrently).
// ---------------------------------------------------------------------------
__global__ __launch_bounds__(512, 2) void traj_transpose_kernel(
        const float* __restrict__ latent, const int* __restrict__ zi,
        const float* __restrict__ w,
        short* __restrict__ zsb, short* __restrict__ wt) {
    __shared__ float tile[64][65];           // transpose path
    __shared__ __align__(16) short zsh[E];   // traj: z as bf16 (A-frag layout)
    __shared__ __align__(16) float red[16];  // traj: per-wave s / s2 partials

    const int tid = threadIdx.x;

    if (blockIdx.x >= BATCH) {
        // ---- transpose + convert: vocab_w (E x V f32) -> wt (V x E bf16) ----
        const int bb = blockIdx.x - BATCH;   // 0..1999
        const int k0 = (bb & 3) * 64;
        const int n0 = (bb >> 2) * 64;
        const int c  = tid & 63;
        const int r8 = tid >> 6;             // 0..7
        #pragma unroll
        for (int r = r8; r < 64; r += 8)
            tile[r][c] = w[(size_t)(k0 + r) * V + n0 + c];
        __syncthreads();
        #pragma unroll
        for (int r = r8; r < 64; r += 8)
            wt[(size_t)(n0 + r) * E + k0 + c] = f2bf(tile[c][r]);
        return;
    }

    // ---- trajectory path: one batch per block, 8 waves ----
    const int b    = blockIdx.x;
    const int lane = tid & 63;
    const int wv   = tid >> 6;       // 0..7, owns cols [32wv, 32wv+32)
    const int lm   = lane & 15;
    const int g    = lane >> 4;      // k-group within fragment
    const float* tr = latent + (size_t)zi[b] * (E * E);

    // B-fragments in registers: B[n][k] = trans[k][n], bf16. 2 tiles x 8 kk.
    s16x8 bfrag[2][8];
    #pragma unroll
    for (int nt = 0; nt < 2; ++nt)
        #pragma unroll
        for (int kk = 0; kk < 8; ++kk) {
            s16x8 fr;
            #pragma unroll
            for (int j = 0; j < 8; ++j)
                fr[j] = f2bf(tr[(size_t)(kk * 32 + g * 8 + j) * E + wv * 32 + nt * 16 + lm]);
            bfrag[nt][kk] = fr;
        }

    // z0 = trans[0, :]
    if (tid < E) zsh[tid] = f2bf(tr[tid]);

    // scale_0 from std(z0) (one-time full reduction)
    {
        float v = (tid < E) ? tr[tid] : 0.f;
        float a = row16_sum(v), a2 = row16_sum(v * v);
        a  += __shfl_xor(a, 16);  a2 += __shfl_xor(a2, 16);
        a  += __shfl_xor(a, 32);  a2 += __shfl_xor(a2, 32);
        if (lane == 0) { red[wv] = a; red[8 + wv] = a2; }
    }
    __syncthreads();

    float scale;
    {
        f32x4 p0 = *(const f32x4*)&red[0], p1 = *(const f32x4*)&red[4];
        f32x4 q0 = *(const f32x4*)&red[8], q1 = *(const f32x4*)&red[12];
        float ts  = (p0[0]+p0[1]+p0[2]+p0[3]) + (p1[0]+p1[1]+p1[2]+p1[3]);
        float ts2 = (q0[0]+q0[1]+q0[2]+q0[3]) + (q1[0]+q1[1]+q1[2]+q1[3]);
        float var = fmaxf((ts2 - ts * ts * (1.0f / 256.0f)) * (1.0f / 255.0f), 0.f);
        scale = 0.113f / (1e-5f + sqrtf(var));
    }
    __syncthreads();

    for (int t = 0; t < NSTEP; ++t) {
        // A-frags: all 16 A-rows = z slice (every C row = emit)
        s16x8 a[8];
        #pragma unroll
        for (int kk = 0; kk < 8; ++kk)
            a[kk] = *(const s16x8*)((const char*)zsh + kk * 64 + g * 16);

        f32x4 acc0 = {}, acc1 = {};
        #pragma unroll
        for (int kk = 0; kk < 8; ++kk) {
            acc0 = __builtin_amdgcn_mfma_f32_16x16x32_bf16(a[kk], bfrag[0][kk], acc0, 0, 0, 0);
            acc1 = __builtin_amdgcn_mfma_f32_16x16x32_bf16(a[kk], bfrag[1][kk], acc1, 0, 0, 0);
        }

        // per-wave Σraw, Σraw² over its 32 cols (DPP, VALU only)
        float u  = row16_sum(acc0[0] + acc1[0]);
        float u2 = row16_sum(acc0[0] * acc0[0] + acc1[0] * acc1[0]);
        if (lane == 0) { red[wv] = u; red[8 + wv] = u2; }
        __syncthreads();

        f32x4 p0 = *(const f32x4*)&red[0], p1 = *(const f32x4*)&red[4];
        f32x4 q0 = *(const f32x4*)&red[8], q1 = *(const f32x4*)&red[12];
        float ts  = (p0[0]+p0[1]+p0[2]+p0[3]) + (p1[0]+p1[1]+p1[2]+p1[3]);
        float ts2 = (q0[0]+q0[1]+q0[2]+q0[3]) + (q1[0]+q1[1]+q1[2]+q1[3]);
        float var = fmaxf((ts2 - ts * ts * (1.0f / 256.0f)) * (1.0f / 255.0f), 0.f);
        float stdr = sqrtf(var);

        // emit = scale_t * raw; store z_{t+1} (bf16) + zsb row
        float e0 = scale * acc0[0], e1 = scale * acc1[0];
        if (g == 0) {
            short b0 = f2bf(e0), b1 = f2bf(e1);
            zsh[wv * 32 + lm]      = b0;
            zsh[wv * 32 + 16 + lm] = b1;
            short* zr = zsb + ((size_t)b * NSTEP + t) * E + wv * 32;
            zr[lm]      = b0;
            zr[16 + lm] = b1;
        }
        // scale_{t+1} = 0.113/(1e-5 + std(z_{t+1})), std(z_{t+1}) = scale_t*std(raw)
        scale = 0.113f / (1e-5f + scale * stdr);
        __syncthreads();
    }
}

// ---------------------------------------------------------------------------
// Kernel 2: 256x128-tile GEMM + fused LSE partials (epilogue reduce via DPP).
// ---------------------------------------------------------------------------
__global__ __launch_bounds__(512, 4) void gemm_lse_kernel(const short* __restrict__ zsb,
                                                          const short* __restrict__ wt,
                                                          const float* __restrict__ vb,
                                                          const int* __restrict__ y,
                                                          float* __restrict__ partial,
                                                          float* __restrict__ logit_y) {
    __shared__ short bpan[BN * E];    // 64 KB

    const int tid  = threadIdx.x;
    const int lane = tid & 63;
    const int w    = tid >> 6;        // 0..7

    const int bid = blockIdx.x;
    const int g   = (bid & 7) * 500 + (bid >> 3);
    const int bn  = g >> 4;
    const int bm  = g & 15;
    const int n0  = bn * BN;
    const int m0  = bm * BM;

    #pragma unroll
    for (int i = 0; i < 8; ++i) {
        const int c   = i * 8 + w;
        const int p   = c * 1024 + lane * 16;
        const int row = p >> 9;
        const int bl  = (p & 511) ^ ((row & 7) << 4);
        gload_lds16((const char*)wt + (size_t)(n0 + row) * (E * 2) + bl,
                    (char*)bpan + c * 1024);
    }

    const int wr = w >> 1, wc = w & 1;
    const int lm = lane & 15, lk = lane >> 4;
    const int mw = m0 + wr * 64;

    __syncthreads();

    f32x4 acc[4][4] = {};
    #pragma unroll
    for (int kk = 0; kk < 8; ++kk) {
        s16x8 a[4], bfr[4];
        #pragma unroll
        for (int rt = 0; rt < 4; ++rt)
            a[rt] = *(const s16x8*)(zsb + (size_t)(mw + rt * 16 + lm) * E + kk * 32 + lk * 8);
        #pragma unroll
        for (int nt = 0; nt < 4; ++nt) {
            const int n_loc = wc * 64 + nt * 16 + lm;
            const int lin   = n_loc * 512 + kk * 64 + lk * 16;
            bfr[nt] = *(const s16x8*)((const char*)bpan + (lin ^ ((n_loc & 7) << 4)));
        }
        #pragma unroll
        for (int rt = 0; rt < 4; ++rt)
            #pragma unroll
            for (int nt = 0; nt < 4; ++nt)
                acc[rt][nt] = __builtin_amdgcn_mfma_f32_16x16x32_bf16(a[rt], bfr[nt], acc[rt][nt], 0, 0, 0);
    }

    const int cr = lane >> 4;
    #pragma unroll
    for (int rt = 0; rt < 4; ++rt) {
        const int rowbase = mw + rt * 16 + cr * 4;
        int yr[4];
        #pragma unroll
        for (int r = 0; r < 4; ++r) yr[r] = y[rowbase + r];

        float rs[4] = {0.f, 0.f, 0.f, 0.f};
        #pragma unroll
        for (int nt = 0; nt < 4; ++nt) {
            const int n_g  = n0 + wc * 64 + nt * 16 + lm;
            const float bias = vb[n_g];
            #pragma unroll
            for (int r = 0; r < 4; ++r) {
                float logit = acc[rt][nt][r] + bias;
                if (n_g == yr[r]) logit_y[rowbase + r] = logit;
                rs[r] += __expf(logit);
            }
        }
        #pragma unroll
        for (int r = 0; r < 4; ++r) rs[r] = row16_sum(rs[r]);   // DPP, not ds_permute
        if (lm == 0) {
            #pragma unroll
            for (int r = 0; r < 4; ++r)
                partial[(size_t)(bn * 2 + wc) * M_TOTAL + rowbase + r] = rs[r];
        }
    }
}

// ---------------------------------------------------------------------------
// Kernel 3: yp[row] = logit_y[row] - log(sum over 500 partials)
// 256 blocks, 16 j-slices x 16 rows per block.
// ---------------------------------------------------------------------------
__global__ __launch_bounds__(256) void finalize_kernel(const float* __restrict__ partial,
                                                       const float* __restrict__ logit_y,
                                                       float* __restrict__ out) {
    __shared__ float s[16][17];
    const int tid = threadIdx.x;
    const int jp = tid >> 4, r = tid & 15;
    const int rowbase = blockIdx.x * 16;

    float acc = 0.f;
    for (int j = jp; j < 2 * NBN; j += 16)
        acc += partial[(size_t)j * M_TOTAL + rowbase + r];
    s[jp][r] = acc;
    __syncthreads();

    if (tid < 16) {
        float t = 0.f;
        #pragma unroll
        for (int k = 0; k < 16; ++k) t += s[k][tid];
        out[rowbase + tid] = logit_y[rowbase + tid] - logf(t);
    }
}

// ---------------------------------------------------------------------------
extern "C" void kernel_launch(void* const* d_in, const int* in_sizes, int n_in,
                              void* d_out, int out_size, void* d_ws, size_t ws_size,
                              hipStream_t stream) {
    const float* latent  = (const float*)d_in[0];
    const float* vocab_w = (const float*)d_in[1];
    const float* vocab_b = (const float*)d_in[2];
    const int*   zi      = (const int*)d_in[3];
    const int*   y       = (const int*)d_in[4];
    float* out = (float*)d_out;

    char* ws = (char*)d_ws;
    float* logit_y = (float*)(ws);                                  // 16 KB
    float* partial = (float*)(ws + 16384);                          // 8 MB
    short* zsb     = (short*)(ws + 16384 + 8192000);                // 2 MB
    short* wt      = (short*)(ws + 16384 + 8192000 + 2097152);      // 16 MB

    hipLaunchKernelGGL(traj_transpose_kernel, dim3(BATCH + 4 * (V / 64)), dim3(512), 0, stream,
                       latent, zi, vocab_w, zsb, wt);
    hipLaunchKernelGGL(gemm_lse_kernel, dim3(16 * NBN), dim3(512), 0, stream,
                       zsb, wt, vocab_b, y, partial, logit_y);
    hipLaunchKernelGGL(finalize_kernel, dim3(M_TOTAL / 16), dim3(256), 0, stream,
                       partial, logit_y, out);
}